// Round 15
// baseline (88.474 us; speedup 1.0000x reference)
//
#include <hip/hip_runtime.h>

#define N_TOK    32768
#define NEMBED   1024
#define SCALE    32.0f   // sqrt(1024)
#define NTHREADS 512     // 8 waves per block

// grid partitioned by output volume (write-BW is the floor):
#define G0 60
#define G1 80    // %4==0 : b1 (K=256, P streamed in pieces), 1 chunk/block
#define G2 308   // %4==0 : b2 (D=64)
#define G3 128   // %4==0 : b3 (D=16)
#define GRID (G0 + G1 + G2 + G3)   // 576

typedef __attribute__((ext_vector_type(8))) short bf16x8;   // 8 bf16 = 4 VGPR
typedef __attribute__((ext_vector_type(4))) float f32x4;    // MFMA acc

__device__ __forceinline__ int bucket_of(int idx) {
    return (idx < 20000) ? 0 : (idx < 40000) ? 1 : (idx < 200000) ? 2 : 3;
}

__device__ __forceinline__ unsigned pk(float a, float b) {   // 2xf32 -> packed bf16 pair (truncate)
    return (__float_as_uint(a) >> 16) | (__float_as_uint(b) & 0xffff0000u);
}
union ABu { bf16x8 v; unsigned u[4]; };
__device__ __forceinline__ bf16x8 make_frag(const float* p) {  // 8 consecutive f32 -> bf16x8
    float4 e0 = *(const float4*)p;
    float4 e1 = *(const float4*)(p + 4);
    ABu a;
    a.u[0] = pk(e0.x, e0.y); a.u[1] = pk(e0.z, e0.w);
    a.u[2] = pk(e1.x, e1.y); a.u[3] = pk(e1.z, e1.w);
    return a.v;
}
__device__ __forceinline__ bf16x8 zero_frag() {
    ABu a; a.u[0] = a.u[1] = a.u[2] = a.u[3] = 0u; return a.v;
}

// ---------------- classify + compact tokens into per-bucket lists ----------------
__global__ void classify_kernel(const int* __restrict__ x,
                                int* __restrict__ cnt,      // [4]
                                int* __restrict__ lists) {  // [4][N_TOK]
    __shared__ int s_cnt[4], s_base[4];
    int tid = threadIdx.x;
    if (tid < 4) s_cnt[tid] = 0;
    __syncthreads();
    int t = blockIdx.x * blockDim.x + tid;
    int b = 0, p = 0;
    if (t < N_TOK) {
        b = bucket_of(x[t]);
        p = atomicAdd(&s_cnt[b], 1);
    }
    __syncthreads();
    if (tid < 4) s_base[tid] = atomicAdd(&cnt[tid], s_cnt[tid]);
    __syncthreads();
    if (t < N_TOK) lists[b * N_TOK + s_base[b] + p] = t;
}

// ---------------- bucket 0: per-wave row copy ----------------
__device__ __forceinline__ void run_copy(const int* __restrict__ x,
                                         const float* __restrict__ table0,
                                         const int* __restrict__ list0,
                                         float* __restrict__ out,
                                         int n, int wv0, int nwv) {
    int lane = threadIdx.x & 63;
    const float4* t4 = (const float4*)table0;
    float4* o4 = (float4*)out;
    #pragma unroll 1
    for (int i = wv0; i < n; i += nwv) {
        int tok = __builtin_amdgcn_readfirstlane(list0[i]);
        int row = __builtin_amdgcn_readfirstlane(x[tok]);
        #pragma unroll
        for (int q = 0; q < 4; ++q) {
            float4 v = t4[(size_t)row * 256 + q * 64 + lane];
            v.x *= SCALE; v.y *= SCALE; v.z *= SCALE; v.w *= SCALE;
            o4[(size_t)tok * 256 + q * 64 + lane] = v;
        }
    }
}

// ---- buckets 2/3: MFMA worker, swapped operands (D = P^T x E -> out[tok] cols per lane).
// P slice (cs of 4, 256 cols) packed fragment-major in LDS once; barrier-free wave jobs.
template <int D>   // 64 or 16
__device__ void run_proj_mfma(const int* __restrict__ x,
                              const float* __restrict__ table,
                              const float* __restrict__ proj,
                              const int* __restrict__ list_b,
                              float* __restrict__ out,
                              int n, int start, int cs,
                              int wj0, int wjs, char* __restrict__ PL) {
    constexpr int KS = (D + 31) / 32;      // k-steps: 2 (D=64) / 1 (D=16, zero-padded)
    int tid = threadIdx.x, lane = tid & 63;

    // ---- pack P[k][col] f32 -> PL[ks][nt][lane][j] bf16 (frag order; lane&15 = P col)
    constexpr int ITEMS = KS * 2048;       // 8-byte units
    #pragma unroll 1
    for (int it = tid; it < ITEMS; it += NTHREADS) {
        int j0 = (it & 1) * 4;
        int ln = (it >> 1) & 63;
        int nt = (it >> 7) & 15;
        int ks = it >> 11;
        int kb = ks * 32 + ((ln >> 4) << 3) + j0;
        int col = cs * 256 + nt * 16 + (ln & 15);
        float f0 = (kb + 0 < D) ? proj[(size_t)(kb + 0) * NEMBED + col] : 0.f;
        float f1 = (kb + 1 < D) ? proj[(size_t)(kb + 1) * NEMBED + col] : 0.f;
        float f2 = (kb + 2 < D) ? proj[(size_t)(kb + 2) * NEMBED + col] : 0.f;
        float f3 = (kb + 3 < D) ? proj[(size_t)(kb + 3) * NEMBED + col] : 0.f;
        *(uint2*)(PL + (((ks * 16 + nt) * 64 + ln) << 4) + j0 * 2) =
            make_uint2(pk(f0, f1), pk(f2, f3));
    }
    __syncthreads();

    int nmt = (n + 15) >> 4;
    #pragma unroll 1
    for (int mt = wj0; mt < nmt; mt += wjs) {
        int ia = mt * 16 + (lane & 15);
        int tok_a = (ia < n) ? list_b[ia] : -1;
        int row_a = (tok_a >= 0) ? (x[tok_a] - start) : 0;
        const float* rp = table + (size_t)row_a * D;
        int k0 = (lane >> 4) << 3;
        bf16x8 e0 = (k0 < D) ? make_frag(rp + k0) : zero_frag();
        f32x4 acc[16];
        #pragma unroll
        for (int nt = 0; nt < 16; ++nt) acc[nt] = f32x4{0.f, 0.f, 0.f, 0.f};
        #pragma unroll
        for (int nt = 0; nt < 16; ++nt) {
            bf16x8 pf = *(const bf16x8*)(PL + ((nt * 64 + lane) << 4));
            acc[nt] = __builtin_amdgcn_mfma_f32_16x16x32_bf16(pf, e0, acc[nt], 0, 0, 0);
        }
        if constexpr (KS == 2) {
            bf16x8 e1 = make_frag(rp + 32 + k0);
            #pragma unroll
            for (int nt = 0; nt < 16; ++nt) {
                bf16x8 pf = *(const bf16x8*)(PL + (((16 + nt) * 64 + lane) << 4));
                acc[nt] = __builtin_amdgcn_mfma_f32_16x16x32_bf16(pf, e1, acc[nt], 0, 0, 0);
            }
        }
        // D mapping (swapped): col=lane&15 -> token (this lane's tok_a);
        // row=(lane>>4)*4+r -> P col -> 4 consecutive floats: one float4 store per nt.
        if (tok_a >= 0) {
            float* op = out + (size_t)tok_a * NEMBED + cs * 256 + ((lane >> 4) << 2);
            #pragma unroll
            for (int nt = 0; nt < 16; ++nt) {
                f32x4 a = acc[nt];
                *(float4*)(op + nt * 16) =
                    make_float4(a[0] * SCALE, a[1] * SCALE, a[2] * SCALE, a[3] * SCALE);
            }
        }
    }
}

// ---- bucket 1: K=256 MFMA, P streamed through LDS in 4 fragment-packed pieces ----
__device__ void run_proj_mfma_big(const int* __restrict__ x,
                                  const float* __restrict__ table,
                                  const float* __restrict__ proj,
                                  const int* __restrict__ list_b,
                                  float* __restrict__ out,
                                  int n, int start, int cs,
                                  int c0, int cstr, char* __restrict__ PL) {
    int tid = threadIdx.x, lane = tid & 63, w = tid >> 6;
    int nch = (n + 127) >> 7;
    #pragma unroll 1
    for (int c = c0; c < nch; c += cstr) {
        int ia = c * 128 + w * 16 + (lane & 15);
        int tok_a = (ia < n) ? list_b[ia] : -1;
        int row_a = (tok_a >= 0) ? (x[tok_a] - start) : 0;
        const float* rp = table + (size_t)row_a * 256;
        f32x4 acc[16];
        #pragma unroll
        for (int nt = 0; nt < 16; ++nt) acc[nt] = f32x4{0.f, 0.f, 0.f, 0.f};

        #pragma unroll 1
        for (int piece = 0; piece < 4; ++piece) {
            __syncthreads();   // previous piece fully consumed
            #pragma unroll 1
            for (int it = tid; it < 4096; it += NTHREADS) {
                int j0 = (it & 1) * 4;
                int ln = (it >> 1) & 63;
                int nt = (it >> 7) & 15;
                int ks = it >> 11;
                int kb = piece * 64 + ks * 32 + ((ln >> 4) << 3) + j0;
                int col = cs * 256 + nt * 16 + (ln & 15);
                float f0 = proj[(size_t)(kb + 0) * NEMBED + col];
                float f1 = proj[(size_t)(kb + 1) * NEMBED + col];
                float f2 = proj[(size_t)(kb + 2) * NEMBED + col];
                float f3 = proj[(size_t)(kb + 3) * NEMBED + col];
                *(uint2*)(PL + (((ks * 16 + nt) * 64 + ln) << 4) + j0 * 2) =
                    make_uint2(pk(f0, f1), pk(f2, f3));
            }
            __syncthreads();
            int k0 = (lane >> 4) << 3;
            bf16x8 e0 = make_frag(rp + piece * 64 + k0);
            bf16x8 e1 = make_frag(rp + piece * 64 + 32 + k0);
            #pragma unroll
            for (int nt = 0; nt < 16; ++nt) {
                bf16x8 pf = *(const bf16x8*)(PL + ((nt * 64 + lane) << 4));
                acc[nt] = __builtin_amdgcn_mfma_f32_16x16x32_bf16(pf, e0, acc[nt], 0, 0, 0);
            }
            #pragma unroll
            for (int nt = 0; nt < 16; ++nt) {
                bf16x8 pf = *(const bf16x8*)(PL + (((16 + nt) * 64 + lane) << 4));
                acc[nt] = __builtin_amdgcn_mfma_f32_16x16x32_bf16(pf, e1, acc[nt], 0, 0, 0);
            }
        }
        if (tok_a >= 0) {
            float* op = out + (size_t)tok_a * NEMBED + cs * 256 + ((lane >> 4) << 2);
            #pragma unroll
            for (int nt = 0; nt < 16; ++nt) {
                f32x4 a = acc[nt];
                *(float4*)(op + nt * 16) =
                    make_float4(a[0] * SCALE, a[1] * SCALE, a[2] * SCALE, a[3] * SCALE);
            }
        }
    }
}

// ---------------- fused kernel: static block partition ----------------
__global__ __launch_bounds__(NTHREADS, 4)
void fused_embed_kernel(const int* __restrict__ x,
                        const float* __restrict__ t0, const float* __restrict__ t1,
                        const float* __restrict__ t2, const float* __restrict__ t3,
                        const float* __restrict__ p1, const float* __restrict__ p2,
                        const float* __restrict__ p3,
                        const int* __restrict__ cnt,
                        const int* __restrict__ lists,
                        float* __restrict__ out) {
    __shared__ __align__(16) char PL[32768];   // 32 KB fragment-packed P
    int bid = blockIdx.x;
    int w = threadIdx.x >> 6;

    if (bid < G0) {
        run_copy(x, t0, lists, out, cnt[0], bid * 8 + w, G0 * 8);
    } else if (bid < G0 + G1) {
        int lb = bid - G0;
        run_proj_mfma_big(x, t1, p1, lists + 1 * N_TOK, out, cnt[1], 20000,
                          lb & 3, lb >> 2, G1 / 4, PL);
    } else if (bid < G0 + G1 + G2) {
        int lb = bid - (G0 + G1);
        run_proj_mfma<64>(x, t2, p2, lists + 2 * N_TOK, out, cnt[2], 40000,
                          lb & 3, (lb >> 2) * 8 + w, (G2 / 4) * 8, PL);
    } else {
        int lb = bid - (G0 + G1 + G2);
        run_proj_mfma<16>(x, t3, p3, lists + 3 * N_TOK, out, cnt[3], 200000,
                          lb & 3, (lb >> 2) * 8 + w, (G3 / 4) * 8, PL);
    }
}

extern "C" void kernel_launch(void* const* d_in, const int* in_sizes, int n_in,
                              void* d_out, int out_size, void* d_ws, size_t ws_size,
                              hipStream_t stream) {
    const int*   x  = (const int*)d_in[0];
    const float* t0 = (const float*)d_in[1];
    const float* t1 = (const float*)d_in[2];
    const float* t2 = (const float*)d_in[3];
    const float* t3 = (const float*)d_in[4];
    const float* p1 = (const float*)d_in[5];
    const float* p2 = (const float*)d_in[6];
    const float* p3 = (const float*)d_in[7];
    float* out = (float*)d_out;

    int* cnt   = (int*)d_ws;
    int* lists = cnt + 64;

    hipMemsetAsync(d_ws, 0, 64 * sizeof(int), stream);
    classify_kernel<<<N_TOK / 256, 256, 0, stream>>>(x, cnt, lists);

    fused_embed_kernel<<<GRID, NTHREADS, 0, stream>>>(x, t0, t1, t2, t3, p1, p2, p3,
                                                      cnt, lists, out);
}

// Round 16
// 45.831 us; speedup vs baseline: 1.9304x; 1.9304x over previous
//
#include <hip/hip_runtime.h>

#define N_TOK    32768
#define NEMBED   1024
#define SCALE    32.0f   // sqrt(1024)
#define NTHREADS 512     // 8 waves per block

// 768 blocks = 3 blocks/CU (48 KB LDS each)
#define G0 72
#define G1 80    // %4==0 : b1 (K=256, P streamed in pieces)
#define G2 440   // %4==0 : b2 (D=64)
#define G3 176   // %4==0 : b3 (D=16)
#define GRID (G0 + G1 + G2 + G3)   // 768

typedef __attribute__((ext_vector_type(8))) short bf16x8;   // 8 bf16 = 4 VGPR
typedef __attribute__((ext_vector_type(4))) float f32x4;    // MFMA acc

__device__ __forceinline__ int bucket_of(int idx) {
    return (idx < 20000) ? 0 : (idx < 40000) ? 1 : (idx < 200000) ? 2 : 3;
}

__device__ __forceinline__ unsigned pk(float a, float b) {   // 2xf32 -> packed bf16 pair
    return (__float_as_uint(a) >> 16) | (__float_as_uint(b) & 0xffff0000u);
}
union ABu { bf16x8 v; unsigned u[4]; };
__device__ __forceinline__ bf16x8 make_frag(const float* p) {  // 8 consecutive f32 -> bf16x8
    float4 e0 = *(const float4*)p;
    float4 e1 = *(const float4*)(p + 4);
    ABu a;
    a.u[0] = pk(e0.x, e0.y); a.u[1] = pk(e0.z, e0.w);
    a.u[2] = pk(e1.x, e1.y); a.u[3] = pk(e1.z, e1.w);
    return a.v;
}
__device__ __forceinline__ bf16x8 zero_frag() {
    ABu a; a.u[0] = a.u[1] = a.u[2] = a.u[3] = 0u; return a.v;
}

// ---- transpose-store: per-wave LDS bounce, 2 nt-tiles per chunk.
// Write: lane(t=lane&15, g=lane>>4) holds D cols (g*4..g*4+3) of token t.
// Read:  8 tokens x 128 B contiguous per instruction (full L2 lines -> no RMW).
__device__ __forceinline__ void store_tile(float* __restrict__ out,
                                           char* __restrict__ TBw,
                                           const f32x4* acc, int tok_a,
                                           int lane, int colbase) {
    int t = lane & 15, g = lane >> 4;
    int th0 = __shfl(tok_a, lane >> 3);
    int th1 = __shfl(tok_a, 8 + (lane >> 3));
    #pragma unroll
    for (int ch = 0; ch < 8; ++ch) {
        int nt0 = ch * 2;
        #pragma unroll
        for (int dnt = 0; dnt < 2; ++dnt) {
            f32x4 a = acc[nt0 + dnt];
            int i = dnt * 4 + g;
            f32x4 s;
            s[0] = a[0] * SCALE; s[1] = a[1] * SCALE;
            s[2] = a[2] * SCALE; s[3] = a[3] * SCALE;
            *(f32x4*)(TBw + ((t * 8 + (i ^ (t & 7))) << 4)) = s;   // swizzled write
        }
        #pragma unroll
        for (int half = 0; half < 2; ++half) {
            int t2 = half * 8 + (lane >> 3);
            int tokd = half ? th1 : th0;
            f32x4 v = *(const f32x4*)(TBw + ((t2 * 8 + ((lane & 7) ^ (t2 & 7))) << 4));
            if (tokd >= 0)
                *(float4*)(out + (size_t)tokd * NEMBED + colbase + nt0 * 16 + (lane & 7) * 4)
                    = make_float4(v[0], v[1], v[2], v[3]);
        }
    }
}

// ---------------- classify + compact tokens into per-bucket lists ----------------
__global__ void classify_kernel(const int* __restrict__ x,
                                int* __restrict__ cnt,      // [4]
                                int* __restrict__ lists) {  // [4][N_TOK]
    __shared__ int s_cnt[4], s_base[4];
    int tid = threadIdx.x;
    if (tid < 4) s_cnt[tid] = 0;
    __syncthreads();
    int t = blockIdx.x * blockDim.x + tid;
    int b = 0, p = 0;
    if (t < N_TOK) {
        b = bucket_of(x[t]);
        p = atomicAdd(&s_cnt[b], 1);
    }
    __syncthreads();
    if (tid < 4) s_base[tid] = atomicAdd(&cnt[tid], s_cnt[tid]);
    __syncthreads();
    if (t < N_TOK) lists[b * N_TOK + s_base[b] + p] = t;
}

// ---------------- bucket 0: per-wave row copy ----------------
__device__ __forceinline__ void run_copy(const int* __restrict__ x,
                                         const float* __restrict__ table0,
                                         const int* __restrict__ list0,
                                         float* __restrict__ out,
                                         int n, int wv0, int nwv) {
    int lane = threadIdx.x & 63;
    const float4* t4 = (const float4*)table0;
    float4* o4 = (float4*)out;
    #pragma unroll 1
    for (int i = wv0; i < n; i += nwv) {
        int tok = __builtin_amdgcn_readfirstlane(list0[i]);
        int row = __builtin_amdgcn_readfirstlane(x[tok]);
        #pragma unroll
        for (int q = 0; q < 4; ++q) {
            float4 v = t4[(size_t)row * 256 + q * 64 + lane];
            v.x *= SCALE; v.y *= SCALE; v.z *= SCALE; v.w *= SCALE;
            o4[(size_t)tok * 256 + q * 64 + lane] = v;
        }
    }
}

// ---- buckets 2/3: MFMA worker, swapped operands; transpose-store epilogue.
template <int D>   // 64 or 16
__device__ void run_proj_mfma(const int* __restrict__ x,
                              const float* __restrict__ table,
                              const float* __restrict__ proj,
                              const int* __restrict__ list_b,
                              float* __restrict__ out,
                              int n, int start, int cs,
                              int wj0, int wjs,
                              char* __restrict__ PL, char* __restrict__ TB) {
    constexpr int KS = (D + 31) / 32;      // 2 (D=64) / 1 (D=16, zero-padded)
    int tid = threadIdx.x, lane = tid & 63;
    char* TBw = TB + (tid >> 6) * 2048;

    // ---- pack P[k][col] f32 -> PL bf16 frag-major (lane&15 = P col)
    constexpr int ITEMS = KS * 2048;       // 8-byte units
    #pragma unroll 1
    for (int it = tid; it < ITEMS; it += NTHREADS) {
        int j0 = (it & 1) * 4;
        int ln = (it >> 1) & 63;
        int nt = (it >> 7) & 15;
        int ks = it >> 11;
        int kb = ks * 32 + ((ln >> 4) << 3) + j0;
        int col = cs * 256 + nt * 16 + (ln & 15);
        float f0 = (kb + 0 < D) ? proj[(size_t)(kb + 0) * NEMBED + col] : 0.f;
        float f1 = (kb + 1 < D) ? proj[(size_t)(kb + 1) * NEMBED + col] : 0.f;
        float f2 = (kb + 2 < D) ? proj[(size_t)(kb + 2) * NEMBED + col] : 0.f;
        float f3 = (kb + 3 < D) ? proj[(size_t)(kb + 3) * NEMBED + col] : 0.f;
        *(uint2*)(PL + (((ks * 16 + nt) * 64 + ln) << 4) + j0 * 2) =
            make_uint2(pk(f0, f1), pk(f2, f3));
    }
    __syncthreads();

    int nmt = (n + 15) >> 4;
    #pragma unroll 1
    for (int mt = wj0; mt < nmt; mt += wjs) {
        int ia = mt * 16 + (lane & 15);
        int tok_a = (ia < n) ? list_b[ia] : -1;
        int row_a = (tok_a >= 0) ? (x[tok_a] - start) : 0;
        const float* rp = table + (size_t)row_a * D;
        int k0 = (lane >> 4) << 3;
        bf16x8 e0 = (k0 < D) ? make_frag(rp + k0) : zero_frag();
        f32x4 acc[16];
        #pragma unroll
        for (int nt = 0; nt < 16; ++nt) acc[nt] = f32x4{0.f, 0.f, 0.f, 0.f};
        #pragma unroll
        for (int nt = 0; nt < 16; ++nt) {
            bf16x8 pf = *(const bf16x8*)(PL + ((nt * 64 + lane) << 4));
            acc[nt] = __builtin_amdgcn_mfma_f32_16x16x32_bf16(pf, e0, acc[nt], 0, 0, 0);
        }
        if constexpr (KS == 2) {
            bf16x8 e1 = make_frag(rp + 32 + k0);
            #pragma unroll
            for (int nt = 0; nt < 16; ++nt) {
                bf16x8 pf = *(const bf16x8*)(PL + (((16 + nt) * 64 + lane) << 4));
                acc[nt] = __builtin_amdgcn_mfma_f32_16x16x32_bf16(pf, e1, acc[nt], 0, 0, 0);
            }
        }
        store_tile(out, TBw, acc, tok_a, lane, cs * 256);
    }
}

// ---- bucket 1: K=256 MFMA, P streamed through LDS in 4 pieces; transpose-store ----
__device__ void run_proj_mfma_big(const int* __restrict__ x,
                                  const float* __restrict__ table,
                                  const float* __restrict__ proj,
                                  const int* __restrict__ list_b,
                                  float* __restrict__ out,
                                  int n, int start, int cs,
                                  int c0, int cstr,
                                  char* __restrict__ PL, char* __restrict__ TB) {
    int tid = threadIdx.x, lane = tid & 63, w = tid >> 6;
    char* TBw = TB + w * 2048;
    int nch = (n + 127) >> 7;
    #pragma unroll 1
    for (int c = c0; c < nch; c += cstr) {
        int ia = c * 128 + w * 16 + (lane & 15);
        int tok_a = (ia < n) ? list_b[ia] : -1;
        int row_a = (tok_a >= 0) ? (x[tok_a] - start) : 0;
        const float* rp = table + (size_t)row_a * 256;
        f32x4 acc[16];
        #pragma unroll
        for (int nt = 0; nt < 16; ++nt) acc[nt] = f32x4{0.f, 0.f, 0.f, 0.f};

        #pragma unroll 1
        for (int piece = 0; piece < 4; ++piece) {
            __syncthreads();   // previous piece fully consumed
            #pragma unroll 1
            for (int it = tid; it < 4096; it += NTHREADS) {
                int j0 = (it & 1) * 4;
                int ln = (it >> 1) & 63;
                int nt = (it >> 7) & 15;
                int ks = it >> 11;
                int kb = piece * 64 + ks * 32 + ((ln >> 4) << 3) + j0;
                int col = cs * 256 + nt * 16 + (ln & 15);
                float f0 = proj[(size_t)(kb + 0) * NEMBED + col];
                float f1 = proj[(size_t)(kb + 1) * NEMBED + col];
                float f2 = proj[(size_t)(kb + 2) * NEMBED + col];
                float f3 = proj[(size_t)(kb + 3) * NEMBED + col];
                *(uint2*)(PL + (((ks * 16 + nt) * 64 + ln) << 4) + j0 * 2) =
                    make_uint2(pk(f0, f1), pk(f2, f3));
            }
            __syncthreads();
            int k0 = (lane >> 4) << 3;
            bf16x8 e0 = make_frag(rp + piece * 64 + k0);
            bf16x8 e1 = make_frag(rp + piece * 64 + 32 + k0);
            #pragma unroll
            for (int nt = 0; nt < 16; ++nt) {
                bf16x8 pf = *(const bf16x8*)(PL + ((nt * 64 + lane) << 4));
                acc[nt] = __builtin_amdgcn_mfma_f32_16x16x32_bf16(pf, e0, acc[nt], 0, 0, 0);
            }
            #pragma unroll
            for (int nt = 0; nt < 16; ++nt) {
                bf16x8 pf = *(const bf16x8*)(PL + (((16 + nt) * 64 + lane) << 4));
                acc[nt] = __builtin_amdgcn_mfma_f32_16x16x32_bf16(pf, e1, acc[nt], 0, 0, 0);
            }
        }
        store_tile(out, TBw, acc, tok_a, lane, cs * 256);
    }
}

// ---------------- fused kernel: static block partition ----------------
__global__ __launch_bounds__(NTHREADS, 4)
void fused_embed_kernel(const int* __restrict__ x,
                        const float* __restrict__ t0, const float* __restrict__ t1,
                        const float* __restrict__ t2, const float* __restrict__ t3,
                        const float* __restrict__ p1, const float* __restrict__ p2,
                        const float* __restrict__ p3,
                        const int* __restrict__ cnt,
                        const int* __restrict__ lists,
                        float* __restrict__ out) {
    __shared__ __align__(16) char SM[49152];   // PL 32 KB + TB 16 KB (8 waves x 2 KB)
    char* PL = SM;
    char* TB = SM + 32768;
    int bid = blockIdx.x;
    int w = threadIdx.x >> 6;

    if (bid < G0) {
        run_copy(x, t0, lists, out, cnt[0], bid * 8 + w, G0 * 8);
    } else if (bid < G0 + G1) {
        int lb = bid - G0;
        run_proj_mfma_big(x, t1, p1, lists + 1 * N_TOK, out, cnt[1], 20000,
                          lb & 3, lb >> 2, G1 / 4, PL, TB);
    } else if (bid < G0 + G1 + G2) {
        int lb = bid - (G0 + G1);
        run_proj_mfma<64>(x, t2, p2, lists + 2 * N_TOK, out, cnt[2], 40000,
                          lb & 3, (lb >> 2) * 8 + w, (G2 / 4) * 8, PL, TB);
    } else {
        int lb = bid - (G0 + G1 + G2);
        run_proj_mfma<16>(x, t3, p3, lists + 3 * N_TOK, out, cnt[3], 200000,
                          lb & 3, (lb >> 2) * 8 + w, (G3 / 4) * 8, PL, TB);
    }
}

extern "C" void kernel_launch(void* const* d_in, const int* in_sizes, int n_in,
                              void* d_out, int out_size, void* d_ws, size_t ws_size,
                              hipStream_t stream) {
    const int*   x  = (const int*)d_in[0];
    const float* t0 = (const float*)d_in[1];
    const float* t1 = (const float*)d_in[2];
    const float* t2 = (const float*)d_in[3];
    const float* t3 = (const float*)d_in[4];
    const float* p1 = (const float*)d_in[5];
    const float* p2 = (const float*)d_in[6];
    const float* p3 = (const float*)d_in[7];
    float* out = (float*)d_out;

    int* cnt   = (int*)d_ws;
    int* lists = cnt + 64;

    hipMemsetAsync(d_ws, 0, 64 * sizeof(int), stream);
    classify_kernel<<<N_TOK / 256, 256, 0, stream>>>(x, cnt, lists);

    fused_embed_kernel<<<GRID, NTHREADS, 0, stream>>>(x, t0, t1, t2, t3, p1, p2, p3,
                                                      cnt, lists, out);
}